// Round 6
// baseline (360.409 us; speedup 1.0000x reference)
//
#include <hip/hip_runtime.h>
#include <hip/hip_fp16.h>

typedef _Float16 f16x8 __attribute__((ext_vector_type(8)));
typedef _Float16 f16x4 __attribute__((ext_vector_type(4)));
typedef float    f32x16 __attribute__((ext_vector_type(16)));
typedef float    f32x4 __attribute__((ext_vector_type(4)));

#define SH 264   // H row stride (fp16): 256+8, 16B-aligned b128
#define SE 56    // E row stride (fp16): 48 used + 8 pad
#define PTS 128  // points per block

struct LayerPtrs {
  const float* w[8];
  const float* b[8];
};

// Weight fragments in d_ws, A-operand layout for mfma_f32_32x32x16_f16:
//   m = mtile*32 + (lane&31), k = kc*16 + (lane>>5)*8 + j ; value = W[k][m]
// index = WOFF[l] + (kc*8 + mtile)*64 + lane, element j.
__global__ void prep_weights(LayerPtrs P, f16x8* __restrict__ wf) {
  int gid = blockIdx.x * 256 + threadIdx.x;
  if (gid >= 60416) return;
  const int OFF[9] = {0,1536,9728,17920,26112,35840,44032,52224,60416};
  int l = 0;
  while (gid >= OFF[l+1]) ++l;
  int f = gid - OFF[l];
  int lane = f & 63;
  int t = f >> 6;
  int mtile = t & 7;
  int kc = t >> 3;
  int col = mtile * 32 + (lane & 31);
  int kb  = (lane >> 5) * 8;
  const float* w = P.w[l];
  f16x8 v;
#pragma unroll
  for (int j = 0; j < 8; ++j) {
    float x = 0.f;
    if (l == 4) {
      if (kc < 3) {
        int k = kc * 16 + kb + j;
        if (k < 39) x = w[k * 256 + col];
      } else {
        int k = (kc - 3) * 16 + kb + j;
        x = w[(39 + k) * 256 + col];
      }
    } else if (l == 0) {
      int k = kc * 16 + kb + j;
      if (k < 39) x = w[k * 256 + col];
    } else {
      int k = kc * 16 + kb + j;
      x = w[k * 256 + col];
    }
    v[j] = (_Float16)x;
  }
  wf[gid] = v;
}

// Wave = 128 hidden (4 m-tiles) x 64 points (2 n-tiles): 8 MFMA per kc,
// fed by 4 global a-frags + only 2 LDS b128 b-frags.
template<int NKC>
__device__ __forceinline__ void mm(const f16x8* __restrict__ wb,
                                   const _Float16* __restrict__ b0,
                                   const _Float16* __restrict__ b1,
                                   f32x16 acc[4][2]) {
#pragma unroll
  for (int kc = 0; kc < NKC; ++kc) {
    f16x8 a0 = wb[(kc * 8 + 0) * 64];
    f16x8 a1 = wb[(kc * 8 + 1) * 64];
    f16x8 a2 = wb[(kc * 8 + 2) * 64];
    f16x8 a3 = wb[(kc * 8 + 3) * 64];
    f16x8 v0 = *(const f16x8*)(b0 + kc * 16);
    f16x8 v1 = *(const f16x8*)(b1 + kc * 16);
    acc[0][0] = __builtin_amdgcn_mfma_f32_32x32x16_f16(a0, v0, acc[0][0], 0, 0, 0);
    acc[0][1] = __builtin_amdgcn_mfma_f32_32x32x16_f16(a0, v1, acc[0][1], 0, 0, 0);
    acc[1][0] = __builtin_amdgcn_mfma_f32_32x32x16_f16(a1, v0, acc[1][0], 0, 0, 0);
    acc[1][1] = __builtin_amdgcn_mfma_f32_32x32x16_f16(a1, v1, acc[1][1], 0, 0, 0);
    acc[2][0] = __builtin_amdgcn_mfma_f32_32x32x16_f16(a2, v0, acc[2][0], 0, 0, 0);
    acc[2][1] = __builtin_amdgcn_mfma_f32_32x32x16_f16(a2, v1, acc[2][1], 0, 0, 0);
    acc[3][0] = __builtin_amdgcn_mfma_f32_32x32x16_f16(a3, v0, acc[3][0], 0, 0, 0);
    acc[3][1] = __builtin_amdgcn_mfma_f32_32x32x16_f16(a3, v1, acc[3][1], 0, 0, 0);
  }
}

// Bias pre-loaded into accumulator (epilogue = relu+cvt+store only).
// C/D 32x32: col(point) = lane&31, row(hidden) = (reg&3) + 8*(reg>>2) + 4*(lane>>5)
__device__ __forceinline__ void init_acc(f32x16 acc[4][2], const float* __restrict__ bp,
                                         int h) {
#pragma unroll
  for (int mt = 0; mt < 4; ++mt)
#pragma unroll
    for (int g = 0; g < 4; ++g) {
      f32x4 bv = *(const f32x4*)&bp[mt * 32 + 8 * g + 4 * h];
#pragma unroll
      for (int nt = 0; nt < 2; ++nt)
#pragma unroll
        for (int r = 0; r < 4; ++r)
          acc[mt][nt][4 * g + r] = bv[r];
    }
}

__device__ __forceinline__ void store_act(f32x16 acc[4][2], int wg, int pg,
                                          int lane, _Float16* __restrict__ H) {
  int p0 = lane & 31, h = lane >> 5;
#pragma unroll
  for (int mt = 0; mt < 4; ++mt) {
    int hb = wg * 128 + mt * 32 + 4 * h;
#pragma unroll
    for (int g = 0; g < 4; ++g) {
#pragma unroll
      for (int nt = 0; nt < 2; ++nt) {
        f16x4 o;
#pragma unroll
        for (int r = 0; r < 4; ++r)
          o[r] = (_Float16)fmaxf(acc[mt][nt][4 * g + r], 0.f);
        *(f16x4*)&H[(pg * 64 + nt * 32 + p0) * SH + hb + 8 * g] = o;
      }
    }
  }
}

__global__ __launch_bounds__(256, 2)
void mlp_fused(const float* __restrict__ points,
               LayerPtrs P,
               const f16x8* __restrict__ wf,
               const float* __restrict__ wsdf,
               const float* __restrict__ bsdf,
               float* __restrict__ out) {
  __shared__ __align__(16) _Float16 H[PTS * SH];   // 67584 B
  __shared__ __align__(16) _Float16 E[PTS * SE];   // 14336 B -> 81920 total, 2 blocks/CU
  const int tid = threadIdx.x;
  const int blk = blockIdx.x;

  // ---- embedding into E: cols 0..38 = [sin(18)|cos(18)|xyz], 39..55 zero ----
  if (tid < PTS) {
    int p = blk * PTS + tid;
    float xyz[3] = {points[p * 3 + 0], points[p * 3 + 1], points[p * 3 + 2]};
    _Float16* row = &E[tid * SE];
#pragma unroll
    for (int c = 0; c < 3; ++c) {
      float fr = 1.f;
#pragma unroll
      for (int k = 0; k < 6; ++k) {
        float e = xyz[c] * fr;
        row[c * 6 + k]      = (_Float16)sinf(e);
        row[18 + c * 6 + k] = (_Float16)cosf(e);
        fr *= 2.f;
      }
      row[36 + c] = (_Float16)xyz[c];
    }
#pragma unroll
    for (int c = 39; c < SE; ++c) row[c] = (_Float16)0.f;
  }
  __syncthreads();

  const int lane = tid & 63;
  const int wv   = tid >> 6;
  const int wg   = wv & 1;            // hidden half  [128*wg, 128*wg+128)
  const int pg   = wv >> 1;           // point half   [64*pg, 64*pg+64)
  const int p0   = lane & 31;
  const int h    = lane >> 5;

  const _Float16* e0 = &E[(pg * 64 +  0 + p0) * SE + h * 8];
  const _Float16* e1 = &E[(pg * 64 + 32 + p0) * SE + h * 8];
  const _Float16* h0 = &H[(pg * 64 +  0 + p0) * SH + h * 8];
  const _Float16* h1 = &H[(pg * 64 + 32 + p0) * SH + h * 8];
  const f16x8* wb = wf + (wg * 4) * 64 + lane;   // + WOFF[l] + (kc*8+mt)*64

  const int WOFF[8] = {0,1536,9728,17920,26112,35840,44032,52224};

  f32x16 acc[4][2];

  // L0: read E, write H (disjoint)
  init_acc(acc, P.b[0] + wg * 128, h);
  mm<3>(wb + WOFF[0], e0, e1, acc);
  store_act(acc, wg, pg, lane, H);
  __syncthreads();

  // L1..L3: in-place H
#pragma unroll
  for (int l = 1; l < 4; ++l) {
    init_acc(acc, P.b[l] + wg * 128, h);
    mm<16>(wb + WOFF[l], h0, h1, acc);
    __syncthreads();
    store_act(acc, wg, pg, lane, H);
    __syncthreads();
  }

  // L4: concat input = E (3 kc) + H (16 kc)
  init_acc(acc, P.b[4] + wg * 128, h);
  mm<3>(wb + WOFF[4], e0, e1, acc);
  mm<16>(wb + WOFF[4] + 3 * 512, h0, h1, acc);
  __syncthreads();
  store_act(acc, wg, pg, lane, H);
  __syncthreads();

  // L5..L7
#pragma unroll
  for (int l = 5; l < 8; ++l) {
    init_acc(acc, P.b[l] + wg * 128, h);
    mm<16>(wb + WOFF[l], h0, h1, acc);
    __syncthreads();
    store_act(acc, wg, pg, lane, H);
    __syncthreads();
  }

  // ---- SDF head: 2 threads per point ----
  {
    const int p = tid >> 1, part = tid & 1;
    float a = 0.f;
    const _Float16* xr = &H[p * SH + part * 128];
#pragma unroll
    for (int j = 0; j < 16; ++j) {
      f16x8 hh = *(const f16x8*)&xr[j * 8];
      f32x4 wa = *(const f32x4*)&wsdf[part * 128 + j * 8];
      f32x4 wc = *(const f32x4*)&wsdf[part * 128 + j * 8 + 4];
      a += (float)hh[0] * wa[0] + (float)hh[1] * wa[1]
         + (float)hh[2] * wa[2] + (float)hh[3] * wa[3]
         + (float)hh[4] * wc[0] + (float)hh[5] * wc[1]
         + (float)hh[6] * wc[2] + (float)hh[7] * wc[3];
    }
    a += __shfl_down(a, 1);
    if (part == 0) out[blk * PTS + p] = a + bsdf[0];
  }
}

extern "C" void kernel_launch(void* const* d_in, const int* in_sizes, int n_in,
                              void* d_out, int out_size, void* d_ws, size_t ws_size,
                              hipStream_t stream) {
  const float* points = (const float*)d_in[0];
  LayerPtrs P;
  for (int i = 0; i < 8; ++i) {
    P.w[i] = (const float*)d_in[1 + 2 * i];
    P.b[i] = (const float*)d_in[2 + 2 * i];
  }
  const float* wsdf = (const float*)d_in[17];
  const float* bsdf = (const float*)d_in[18];
  f16x8* wf = (f16x8*)d_ws;   // needs 966656 B

  int N = in_sizes[0] / 3;    // 262144
  prep_weights<<<236, 256, 0, stream>>>(P, wf);
  mlp_fused<<<N / PTS, 256, 0, stream>>>(points, P, wf, wsdf, bsdf, (float*)d_out);
}

// Round 7
// 317.906 us; speedup vs baseline: 1.1337x; 1.1337x over previous
//
#include <hip/hip_runtime.h>
#include <hip/hip_fp16.h>

typedef _Float16 f16x8 __attribute__((ext_vector_type(8)));
typedef _Float16 f16x4 __attribute__((ext_vector_type(4)));
typedef float    f32x16 __attribute__((ext_vector_type(16)));
typedef float    f32x4 __attribute__((ext_vector_type(4)));

#define PTS 128  // points per block

struct LayerPtrs {
  const float* w[8];
  const float* b[8];
};

// Weight fragments in d_ws, A-operand layout for mfma_f32_32x32x16_f16:
//   m = mtile*32 + (lane&31), k = kc*16 + (lane>>5)*8 + j ; value = W[k][m]
// index = WOFF[l] + (kc*8 + mtile)*64 + lane, element j.
__global__ void prep_weights(LayerPtrs P, f16x8* __restrict__ wf) {
  int gid = blockIdx.x * 256 + threadIdx.x;
  if (gid >= 60416) return;
  const int OFF[9] = {0,1536,9728,17920,26112,35840,44032,52224,60416};
  int l = 0;
  while (gid >= OFF[l+1]) ++l;
  int f = gid - OFF[l];
  int lane = f & 63;
  int t = f >> 6;
  int mtile = t & 7;
  int kc = t >> 3;
  int col = mtile * 32 + (lane & 31);
  int kb  = (lane >> 5) * 8;
  const float* w = P.w[l];
  f16x8 v;
#pragma unroll
  for (int j = 0; j < 8; ++j) {
    float x = 0.f;
    if (l == 4) {
      if (kc < 3) {
        int k = kc * 16 + kb + j;
        if (k < 39) x = w[k * 256 + col];
      } else {
        int k = (kc - 3) * 16 + kb + j;
        x = w[(39 + k) * 256 + col];
      }
    } else if (l == 0) {
      int k = kc * 16 + kb + j;
      if (k < 39) x = w[k * 256 + col];
    } else {
      int k = kc * 16 + kb + j;
      x = w[k * 256 + col];
    }
    v[j] = (_Float16)x;
  }
  wf[gid] = v;
}

// Activations chunk-major in LDS: HB[c*PTS + p] = hidden chunk c (8 f16) of point p.
// B-frag read for (kc, nt): lane (p0,h) -> HB[(2kc+h)*PTS + nt*32 + p0]
//   -> 16 B lane stride -> all 32 banks -> conflict-free.
template<int NKC>
__device__ __forceinline__ void mm(const f16x8* __restrict__ wb,
                                   const f16x8* __restrict__ b,   // base + h*PTS + p0
                                   f32x16 acc[2][4]) {
#pragma unroll
  for (int kc = 0; kc < NKC; ++kc) {
    f16x8 a0 = wb[(kc * 8 + 0) * 64];
    f16x8 a1 = wb[(kc * 8 + 1) * 64];
    f16x8 v0 = b[kc * 2 * PTS + 0];
    f16x8 v1 = b[kc * 2 * PTS + 32];
    f16x8 v2 = b[kc * 2 * PTS + 64];
    f16x8 v3 = b[kc * 2 * PTS + 96];
    acc[0][0] = __builtin_amdgcn_mfma_f32_32x32x16_f16(a0, v0, acc[0][0], 0, 0, 0);
    acc[0][1] = __builtin_amdgcn_mfma_f32_32x32x16_f16(a0, v1, acc[0][1], 0, 0, 0);
    acc[0][2] = __builtin_amdgcn_mfma_f32_32x32x16_f16(a0, v2, acc[0][2], 0, 0, 0);
    acc[0][3] = __builtin_amdgcn_mfma_f32_32x32x16_f16(a0, v3, acc[0][3], 0, 0, 0);
    acc[1][0] = __builtin_amdgcn_mfma_f32_32x32x16_f16(a1, v0, acc[1][0], 0, 0, 0);
    acc[1][1] = __builtin_amdgcn_mfma_f32_32x32x16_f16(a1, v1, acc[1][1], 0, 0, 0);
    acc[1][2] = __builtin_amdgcn_mfma_f32_32x32x16_f16(a1, v2, acc[1][2], 0, 0, 0);
    acc[1][3] = __builtin_amdgcn_mfma_f32_32x32x16_f16(a1, v3, acc[1][3], 0, 0, 0);
  }
}

// Bias pre-loaded into accumulator.
// C/D 32x32: col(point) = lane&31, row(hidden) = (reg&3) + 8*(reg>>2) + 4*(lane>>5)
__device__ __forceinline__ void init_acc(f32x16 acc[2][4], const float* __restrict__ bp,
                                         int h) {
#pragma unroll
  for (int mt = 0; mt < 2; ++mt)
#pragma unroll
    for (int g = 0; g < 4; ++g) {
      f32x4 bv = *(const f32x4*)&bp[mt * 32 + 8 * g + 4 * h];
#pragma unroll
      for (int nt = 0; nt < 4; ++nt)
#pragma unroll
        for (int r = 0; r < 4; ++r)
          acc[mt][nt][4 * g + r] = bv[r];
    }
}

// hidden = wv*64 + mt*32 + 8g + 4h + r -> chunk c = wv*8 + mt*4 + g, f16 offset 4h+r.
// f16x4 write, 16 B lane stride in p0, h selects 8 B half -> 4 dwords/bank = min cycles.
__device__ __forceinline__ void store_act(f32x16 acc[2][4], int wv,
                                          int lane, f16x8* __restrict__ HB) {
  int p0 = lane & 31, h = lane >> 5;
#pragma unroll
  for (int mt = 0; mt < 2; ++mt) {
#pragma unroll
    for (int g = 0; g < 4; ++g) {
      int c = wv * 8 + mt * 4 + g;
#pragma unroll
      for (int nt = 0; nt < 4; ++nt) {
        f16x4 o;
#pragma unroll
        for (int r = 0; r < 4; ++r)
          o[r] = (_Float16)fmaxf(acc[mt][nt][4 * g + r], 0.f);
        *(f16x4*)((_Float16*)&HB[c * PTS + nt * 32 + p0] + 4 * h) = o;
      }
    }
  }
}

__global__ __launch_bounds__(256, 2)
void mlp_fused(const float* __restrict__ points,
               LayerPtrs P,
               const f16x8* __restrict__ wf,
               const float* __restrict__ wsdf,
               const float* __restrict__ bsdf,
               float* __restrict__ out) {
  __shared__ __align__(16) f16x8 HB[32 * PTS];   // 65536 B
  __shared__ __align__(16) f16x8 EB[6 * PTS];    // 12288 B -> 77824 total, 2 blocks/CU
  const int tid = threadIdx.x;
  const int blk = blockIdx.x;

  // ---- embedding, chunk-major: cols 0..38 = [sin(18)|cos(18)|xyz], 39..47 zero ----
  if (tid < PTS) {
    int p = blk * PTS + tid;
    float xyz[3] = {points[p * 3 + 0], points[p * 3 + 1], points[p * 3 + 2]};
    _Float16 row[48];
#pragma unroll
    for (int c = 0; c < 3; ++c) {
      float fr = 1.f;
#pragma unroll
      for (int k = 0; k < 6; ++k) {
        float e = xyz[c] * fr;
        row[c * 6 + k]      = (_Float16)sinf(e);
        row[18 + c * 6 + k] = (_Float16)cosf(e);
        fr *= 2.f;
      }
      row[36 + c] = (_Float16)xyz[c];
    }
#pragma unroll
    for (int c = 39; c < 48; ++c) row[c] = (_Float16)0.f;
#pragma unroll
    for (int c = 0; c < 6; ++c)
      EB[c * PTS + tid] = *(const f16x8*)&row[c * 8];
  }
  __syncthreads();

  const int lane = tid & 63;
  const int wv   = tid >> 6;          // wave -> hidden slice [64*wv, 64*wv+64)
  const int p0   = lane & 31;
  const int h    = lane >> 5;

  const f16x8* eb = &EB[h * PTS + p0];
  const f16x8* hb = &HB[h * PTS + p0];
  const f16x8* wb = wf + (wv * 2) * 64 + lane;   // + WOFF[l] + (kc*8+mt)*64

  const int WOFF[8] = {0,1536,9728,17920,26112,35840,44032,52224};

  f32x16 acc[2][4];

  // L0: read E, write H (disjoint)
  init_acc(acc, P.b[0] + wv * 64, h);
  mm<3>(wb + WOFF[0], eb, acc);
  store_act(acc, wv, lane, HB);
  __syncthreads();

  // L1..L3: in-place H
#pragma unroll
  for (int l = 1; l < 4; ++l) {
    init_acc(acc, P.b[l] + wv * 64, h);
    mm<16>(wb + WOFF[l], hb, acc);
    __syncthreads();
    store_act(acc, wv, lane, HB);
    __syncthreads();
  }

  // L4: concat input = E (3 kc) + H (16 kc)
  init_acc(acc, P.b[4] + wv * 64, h);
  mm<3>(wb + WOFF[4], eb, acc);
  mm<16>(wb + WOFF[4] + 3 * 512, hb, acc);
  __syncthreads();
  store_act(acc, wv, lane, HB);
  __syncthreads();

  // L5..L7
#pragma unroll
  for (int l = 5; l < 8; ++l) {
    init_acc(acc, P.b[l] + wv * 64, h);
    mm<16>(wb + WOFF[l], hb, acc);
    __syncthreads();
    store_act(acc, wv, lane, HB);
    __syncthreads();
  }

  // ---- SDF head: 2 threads per point; chunk-major reads are conflict-free ----
  {
    const int p = tid >> 1, part = tid & 1;
    float a = 0.f;
#pragma unroll
    for (int c2 = 0; c2 < 16; ++c2) {
      f16x8 hh = HB[(part * 16 + c2) * PTS + p];
      f32x4 wa = *(const f32x4*)&wsdf[(part * 16 + c2) * 8];
      f32x4 wc = *(const f32x4*)&wsdf[(part * 16 + c2) * 8 + 4];
      a += (float)hh[0] * wa[0] + (float)hh[1] * wa[1]
         + (float)hh[2] * wa[2] + (float)hh[3] * wa[3]
         + (float)hh[4] * wc[0] + (float)hh[5] * wc[1]
         + (float)hh[6] * wc[2] + (float)hh[7] * wc[3];
    }
    a += __shfl_down(a, 1);
    if (part == 0) out[blk * PTS + p] = a + bsdf[0];
  }
}

extern "C" void kernel_launch(void* const* d_in, const int* in_sizes, int n_in,
                              void* d_out, int out_size, void* d_ws, size_t ws_size,
                              hipStream_t stream) {
  const float* points = (const float*)d_in[0];
  LayerPtrs P;
  for (int i = 0; i < 8; ++i) {
    P.w[i] = (const float*)d_in[1 + 2 * i];
    P.b[i] = (const float*)d_in[2 + 2 * i];
  }
  const float* wsdf = (const float*)d_in[17];
  const float* bsdf = (const float*)d_in[18];
  f16x8* wf = (f16x8*)d_ws;   // needs 966656 B

  int N = in_sizes[0] / 3;    // 262144
  prep_weights<<<236, 256, 0, stream>>>(P, wf);
  mlp_fused<<<N / PTS, 256, 0, stream>>>(points, P, wf, wsdf, bsdf, (float*)d_out);
}